// Round 1
// baseline (830.894 us; speedup 1.0000x reference)
//
#include <hip/hip_runtime.h>

// Correlation layer: out[b, dh*9+dw, h, w] =
//   (1/196) * sum_c in1[b,c,h,w] * in2[b,c, refl(h+dh-4), refl(w+dw-4)]
// Shapes: in1,in2 = [8,196,128,224] f32 ; out = [8,81,128,224] f32
//
// v2: double-buffered LDS (ONE barrier per round, staging writes off the
// critical path, compute-first round order), XCD-contiguous block swizzle
// (each XCD owns one batch b -> 9x in2 row reuse served from its L2),
// WS 232->236 to spread LDS row bank phases.

constexpr int NB = 8, NC = 196, NH = 128, NW = 224;
constexpr int ND = 9;            // displacements per axis
constexpr int PADV = 4;
constexpr int WS = 236;          // staged row stride (floats): 232 used + 4 pad
constexpr int KC = 2;            // channels per round
constexpr int NSLOT = 56;        // w-groups of 4
constexpr int ACTIVE = ND * NSLOT;   // 504 compute threads
constexpr int TPB = 512;
constexpr int HWSZ = NH * NW;    // 28672
constexpr int NR = NC / KC;      // 98 rounds
constexpr int NXCD = 8;
constexpr int NBLK = NB * NH;    // 1024 blocks = 8 XCD * 128

__device__ __forceinline__ int refl(int v, int n) {
    v = v < 0 ? -v : v;
    return v >= n ? 2 * n - 2 - v : v;
}

__global__ __launch_bounds__(TPB)
void corr_kernel(const float* __restrict__ in1,
                 const float* __restrict__ in2,
                 float* __restrict__ out)
{
    __shared__ __align__(16) float s_win[2][KC][ND][WS];   // 33,984 B

    const int tid = threadIdx.x;
    // XCD-contiguous remap: hardware round-robins blockIdx across 8 XCDs;
    // remap so XCD x gets bh in [x*128,(x+1)*128) == batch b=x, all h.
    // Neighboring-h blocks then share staged in2 rows inside one L2.
    const int bh = (blockIdx.x & (NXCD - 1)) * (NBLK / NXCD) + (blockIdx.x >> 3);
    const int b   = bh / NH;
    const int h   = bh - b * NH;

    // ---- staging precompute (fixed across channel rounds) ----
    // Part A: interior vector slots: KC*ND*56 = 1008 float4 slots
    const float* gA[2];
    int  lA[2];
    bool vA[2];
#pragma unroll
    for (int k = 0; k < 2; ++k) {
        int v  = tid + k * TPB;
        vA[k]  = v < KC * ND * NSLOT;
        int vv = vA[k] ? v : 0;
        int cc = vv / (ND * NSLOT);
        int r  = vv - cc * (ND * NSLOT);
        int dh = r / NSLOT;
        int g  = r - dh * NSLOT;
        int y  = refl(h + dh - PADV, NH);
        gA[k]  = in2 + ((b * NC + cc) * NH + y) * NW + 4 * g;
        lA[k]  = (cc * ND + dh) * WS + 4 + 4 * g;
    }
    // Part B: edge scalar slots: KC*ND*8 = 144
    const float* gB = in2;
    int  lB = 0;
    const bool vB = tid < KC * ND * 8;
    {
        int v  = vB ? tid : 0;
        int cc = v / (ND * 8);
        int r  = v - cc * (ND * 8);
        int dh = r / 8;
        int e  = r - dh * 8;
        int s  = e < 4 ? e : 224 + e;
        int x  = e < 4 ? 4 - e : 226 - e;
        int y  = refl(h + dh - PADV, NH);
        gB = in2 + ((b * NC + cc) * NH + y) * NW + x;
        lB = (cc * ND + dh) * WS + s;
    }

    // ---- compute-thread identity (dh-major) ----
    const int  cdh  = tid / NSLOT;          // 0..8
    const int  slot = tid - cdh * NSLOT;    // 0..55
    const int  w0   = slot * 4;
    const bool compute = tid < ACTIVE;
    const float* a1p = in1 + ((b * NC) * NH + h) * NW + w0;

    float acc[ND][4];
#pragma unroll
    for (int d = 0; d < ND; ++d)
#pragma unroll
        for (int p = 0; p < 4; ++p) acc[d][p] = 0.f;

    // ---- prologue: round 0 -> buf0; round-1 loads left in flight ----
    float4 bufA[2];
    float  bufB = 0.f;
#pragma unroll
    for (int k = 0; k < 2; ++k)
        if (vA[k]) bufA[k] = *(const float4*)(gA[k]);
    if (vB) bufB = gB[0];
    {
        float* dst = &s_win[0][0][0][0];
#pragma unroll
        for (int k = 0; k < 2; ++k)
            if (vA[k]) *(float4*)(dst + lA[k]) = bufA[k];
        if (vB) dst[lB] = bufB;
    }
#pragma unroll
    for (int k = 0; k < 2; ++k)
        if (vA[k]) bufA[k] = *(const float4*)(gA[k] + KC * HWSZ);
    if (vB) bufB = gB[KC * HWSZ];
    __syncthreads();

    // ---- main loop: ONE barrier per round ----
    // round r: compute from s_win[r&1] (ready); write prefetched regs
    // (round r+1 data) into s_win[r&1 ^ 1]; issue loads for round r+2;
    // barrier. The vmcnt wait for the staged regs sits AFTER compute issue.
    for (int r = 0; r < NR; ++r) {
        const int cur = r & 1;

        if (compute) {
#pragma unroll
            for (int cc = 0; cc < KC; ++cc) {
                const float* wrow = &s_win[cur][cc][cdh][w0];
                float4 wv0 = *(const float4*)(wrow);
                float4 wv1 = *(const float4*)(wrow + 4);
                float4 wv2 = *(const float4*)(wrow + 8);
                const float wn[12] = {wv0.x, wv0.y, wv0.z, wv0.w,
                                      wv1.x, wv1.y, wv1.z, wv1.w,
                                      wv2.x, wv2.y, wv2.z, wv2.w};
                float4 a = *(const float4*)(a1p + (r * KC + cc) * HWSZ);
#pragma unroll
                for (int d = 0; d < ND; ++d) {
                    acc[d][0] += a.x * wn[d + 0];
                    acc[d][1] += a.y * wn[d + 1];
                    acc[d][2] += a.z * wn[d + 2];
                    acc[d][3] += a.w * wn[d + 3];
                }
            }
        }

        if (r + 1 < NR) {
            // stage round r+1 (regs loaded during round r-1) into the other buffer
            float* dst = &s_win[cur ^ 1][0][0][0];
#pragma unroll
            for (int k = 0; k < 2; ++k)
                if (vA[k]) *(float4*)(dst + lA[k]) = bufA[k];
            if (vB) dst[lB] = bufB;
            // issue next round-pair's global loads (consumed next round)
            if (r + 2 < NR) {
                const int off = (r + 2) * KC * HWSZ;
#pragma unroll
                for (int k = 0; k < 2; ++k)
                    if (vA[k]) bufA[k] = *(const float4*)(gA[k] + off);
                if (vB) bufB = gB[off];
            }
        }
        __syncthreads();
    }

    if (compute) {
        const float scale = 1.0f / 196.0f;
#pragma unroll
        for (int d = 0; d < ND; ++d) {
            float4 o;
            o.x = acc[d][0] * scale;
            o.y = acc[d][1] * scale;
            o.z = acc[d][2] * scale;
            o.w = acc[d][3] * scale;
            float* op = out + (((b * (ND * ND)) + cdh * ND + d) * NH + h) * NW + w0;
            *(float4*)op = o;
        }
    }
}

extern "C" void kernel_launch(void* const* d_in, const int* in_sizes, int n_in,
                              void* d_out, int out_size, void* d_ws, size_t ws_size,
                              hipStream_t stream)
{
    const float* in1 = (const float*)d_in[0];
    const float* in2 = (const float*)d_in[1];
    float* outp = (float*)d_out;
    dim3 grid(NBLK);
    dim3 block(TPB);
    hipLaunchKernelGGL(corr_kernel, grid, block, 0, stream, in1, in2, outp);
}